// Round 7
// baseline (581.981 us; speedup 1.0000x reference)
//
#include <hip/hip_runtime.h>
#include <hip/hip_bf16.h>
#include <cstddef>
#include <cstdint>

// Problem constants
#define V 32000
#define E 512
#define H 512
#define B 32
#define T 20
#define BPB 8   // batches per block in lstm_step (grid.y = B/BPB = 4)

typedef __bf16 bf16x8 __attribute__((ext_vector_type(8)));
typedef float f32x4 __attribute__((ext_vector_type(4)));
typedef unsigned short ushort8_t __attribute__((ext_vector_type(8)));

__device__ __forceinline__ float sigmoidf_(float x) { return 1.f / (1.f + expf(-x)); }

// f32 -> bf16 round-to-nearest-even (bit pattern)
__device__ __forceinline__ unsigned short f2bf(float f) {
    unsigned int u = __builtin_bit_cast(unsigned int, f);
    u += 0x7FFFu + ((u >> 16) & 1u);
    return (unsigned short)(u >> 16);
}

// ---------------------------------------------------------------------------
// W_out (32000x512 f32) -> bf16. 8 elems/thread, fully coalesced.
// ---------------------------------------------------------------------------
__global__ __launch_bounds__(256) void wout_to_bf16(const float* __restrict__ src,
                                                    unsigned short* __restrict__ dst)
{
    const size_t i = ((size_t)blockIdx.x * 256 + threadIdx.x) * 8;
    float4 a = *(const float4*)(src + i);
    float4 b = *(const float4*)(src + i + 4);
    ushort8_t o;
    o[0] = f2bf(a.x); o[1] = f2bf(a.y); o[2] = f2bf(a.z); o[3] = f2bf(a.w);
    o[4] = f2bf(b.x); o[5] = f2bf(b.y); o[6] = f2bf(b.z); o[7] = f2bf(b.w);
    *(ushort8_t*)(dst + i) = o;
}

// ---------------------------------------------------------------------------
// LSTM cell step. One wave per hidden index (512 waves) x 4 batch-groups:
// grid = (128, 4). Each wave holds its W rows in registers and loops over
// BPB=8 batches with butterfly reduce. step==0: x=features, h=c=0.
// h_seq written in bf16 (GEMM A operand). Batch groups are disjoint:
// no cross-block communication.
// ---------------------------------------------------------------------------
__global__ __launch_bounds__(256) void lstm_step(
    const float* __restrict__ features, const int* __restrict__ captions,
    const float* __restrict__ emb,
    const float* __restrict__ W_ih, const float* __restrict__ W_hh,
    const float* __restrict__ b_ih, const float* __restrict__ b_hh,
    const float* __restrict__ h_in, const float* __restrict__ c_in,
    float* __restrict__ h_out, float* __restrict__ c_out,
    unsigned short* __restrict__ h_seq_bf, int step)
{
    const int lane = threadIdx.x & 63;
    const int hidx = (blockIdx.x * 256 + threadIdx.x) >> 6;  // 0..511
    const int b0 = blockIdx.y * BPB;

    float wi[4][8], wh[4][8];
    float bias[4];
#pragma unroll
    for (int g = 0; g < 4; ++g) {
        const int row = g * H + hidx;
        bias[g] = b_ih[row] + b_hh[row];
        const float* wr = W_ih + (size_t)row * E;
#pragma unroll
        for (int k = 0; k < 8; ++k) wi[g][k] = wr[k * 64 + lane];
    }
    if (step > 0) {
#pragma unroll
        for (int g = 0; g < 4; ++g) {
            const float* wr = W_hh + (size_t)(g * H + hidx) * H;
#pragma unroll
            for (int k = 0; k < 8; ++k) wh[g][k] = wr[k * 64 + lane];
        }
    }

    for (int b = b0; b < b0 + BPB; ++b) {
        const float* xb = (step == 0)
                              ? (features + (size_t)b * E)
                              : (emb + (size_t)captions[b * T + (step - 1)] * E);
        float acc[4] = {0.f, 0.f, 0.f, 0.f};
#pragma unroll
        for (int k = 0; k < 8; ++k) {
            float xv = xb[k * 64 + lane];
#pragma unroll
            for (int g = 0; g < 4; ++g) acc[g] += xv * wi[g][k];
        }
        if (step > 0) {
            const float* hb = h_in + (size_t)b * H;
#pragma unroll
            for (int k = 0; k < 8; ++k) {
                float hv = hb[k * 64 + lane];
#pragma unroll
                for (int g = 0; g < 4; ++g) acc[g] += hv * wh[g][k];
            }
        }
#pragma unroll
        for (int off = 32; off > 0; off >>= 1) {
#pragma unroll
            for (int g = 0; g < 4; ++g) acc[g] += __shfl_xor(acc[g], off);
        }
        if (lane == 0) {
            float iv = sigmoidf_(acc[0] + bias[0]);
            float fv = sigmoidf_(acc[1] + bias[1]);
            float gv = tanhf(acc[2] + bias[2]);
            float ov = sigmoidf_(acc[3] + bias[3]);
            float cp = (step == 0) ? 0.f : c_in[(size_t)b * H + hidx];
            float cn = fv * cp + iv * gv;
            float hn = ov * tanhf(cn);
            c_out[(size_t)b * H + hidx] = cn;
            h_out[(size_t)b * H + hidx] = hn;
            if (step > 0)
                h_seq_bf[(size_t)((step - 1) * B + b) * H + hidx] = f2bf(hn);
        }
    }
}

// ---------------------------------------------------------------------------
// Projection GEMM (bf16 MFMA): C[m][n] = A[m][:].Wout[n][:] + bias[n]
// A (640x512 bf16, K-major), Wout (32000x512 bf16, K-major).
// 128x128 tile, BK=32, 256 threads = 4 waves, each wave 64x64 quadrant as
// 4x4 fragments of mfma_f32_16x16x32_bf16.
// LDS layout: 16B chunks indexed [kchunk(0..3)][row(0..127)] per operand —
// linear for global_load_lds (dest = wave base + lane*16) and conflict-free
// for the ds_read_b128 fragment reads (consecutive rows -> consecutive chunks).
// Epilogue scatters into out[(b*(T+1) + t + 1)*V + n] with m = t*32 + b.
// ---------------------------------------------------------------------------
__global__ __launch_bounds__(256) void proj_gemm(
    const unsigned short* __restrict__ Abf,
    const unsigned short* __restrict__ Wbf,
    const float* __restrict__ bias, float* __restrict__ out)
{
    __shared__ __align__(16) unsigned short smem[8192];  // A: 4096, B: 4096 elems
    const int tid = threadIdx.x;
    const int lane = tid & 63, wid = tid >> 6;
    const int mbase = blockIdx.y * 128, nbase = blockIdx.x * 128;
    const int wr = wid >> 1, wc = wid & 1;

    // per-lane global source for the 4 staging calls (chunk c = j*256 + wid*64 + lane)
    const unsigned short* srcs[4];
    unsigned short* ldsw[4];
#pragma unroll
    for (int j = 0; j < 4; ++j) {
        const int c = j * 256 + wid * 64 + lane;
        const int cc = c & 511;
        const int q = cc >> 7, row = cc & 127;
        srcs[j] = (c < 512 ? Abf + (size_t)(mbase + row) * 512
                           : Wbf + (size_t)(nbase + row) * 512) + q * 8;
        ldsw[j] = smem + (size_t)(j * 256 + wid * 64) * 8;  // wave-uniform
    }

    f32x4 acc[4][4];
#pragma unroll
    for (int i = 0; i < 4; ++i)
#pragma unroll
        for (int j = 0; j < 4; ++j) acc[i][j] = (f32x4){0.f, 0.f, 0.f, 0.f};

    const int qrow = (lane >> 4) * 128;
    const unsigned short* aptr = smem + (size_t)(qrow + wr * 64 + (lane & 15)) * 8;
    const unsigned short* bptr = smem + (size_t)(4096 / 8 + qrow + wc * 64 + (lane & 15)) * 8;

    for (int k0 = 0; k0 < 512; k0 += 32) {
#pragma unroll
        for (int j = 0; j < 4; ++j)
            __builtin_amdgcn_global_load_lds(
                (const __attribute__((address_space(1))) void*)(srcs[j] + k0),
                (__attribute__((address_space(3))) void*)ldsw[j], 16, 0, 0);
        __syncthreads();  // drains vmcnt: staged data visible
        bf16x8 af[4], bv[4];
#pragma unroll
        for (int i = 0; i < 4; ++i) {
            af[i] = *(const bf16x8*)(aptr + i * 128);   // +16 rows = 16 chunks = 128 elems
            bv[i] = *(const bf16x8*)(bptr + i * 128);
        }
#pragma unroll
        for (int mi = 0; mi < 4; ++mi)
#pragma unroll
            for (int ni = 0; ni < 4; ++ni)
                acc[mi][ni] = __builtin_amdgcn_mfma_f32_16x16x32_bf16(
                    af[mi], bv[ni], acc[mi][ni], 0, 0, 0);
        __syncthreads();  // all waves done reading before next stage
    }

    // epilogue: C/D layout col = lane&15, row = (lane>>4)*4 + reg
    const int col0 = wc * 64 + (lane & 15);
    const int r0 = (lane >> 4) * 4;
#pragma unroll
    for (int mi = 0; mi < 4; ++mi) {
#pragma unroll
        for (int r = 0; r < 4; ++r) {
            const int m = mbase + wr * 64 + mi * 16 + r0 + r;
            const int t = m >> 5;   // m / 32
            const int b = m & 31;   // m % 32
            float* op = out + (size_t)(b * (T + 1) + t + 1) * V + nbase;
#pragma unroll
            for (int ni = 0; ni < 4; ++ni) {
                const int n = col0 + ni * 16;
                op[n] = acc[mi][ni][r] + bias[nbase + n];
            }
        }
    }
}

// ---------------------------------------------------------------------------
// out[:, 0, :] = one-hot at index 1
// ---------------------------------------------------------------------------
__global__ __launch_bounds__(256) void start_onehot(float* __restrict__ out)
{
    const int v = blockIdx.x * 256 + threadIdx.x;  // grid.x = 125
    const int b = blockIdx.y;
    out[(size_t)b * (T + 1) * V + v] = (v == 1) ? 1.f : 0.f;
}

// ---------------------------------------------------------------------------
extern "C" void kernel_launch(void* const* d_in, const int* in_sizes, int n_in,
                              void* d_out, int out_size, void* d_ws, size_t ws_size,
                              hipStream_t stream)
{
    const float* features = (const float*)d_in[0];
    const int*   captions = (const int*)d_in[1];
    const float* emb      = (const float*)d_in[2];
    const float* W_ih     = (const float*)d_in[3];
    const float* W_hh     = (const float*)d_in[4];
    const float* b_ih     = (const float*)d_in[5];
    const float* b_hh     = (const float*)d_in[6];
    const float* W_out    = (const float*)d_in[7];
    const float* b_out    = (const float*)d_in[8];
    float* out = (float*)d_out;

    // workspace layout
    float* h0 = (float*)d_ws;                       // B*H f32
    float* c0 = h0 + B * H;
    float* h1 = c0 + B * H;
    float* c1 = h1 + B * H;
    unsigned short* hseq_bf = (unsigned short*)(c1 + B * H);   // T*B*H bf16
    unsigned short* wout_bf = hseq_bf + (size_t)T * B * H;     // V*H bf16 (32.8 MB)

    hipLaunchKernelGGL(wout_to_bf16, dim3((V * H) / (256 * 8)), dim3(256), 0, stream,
                       W_out, wout_bf);
    hipLaunchKernelGGL(start_onehot, dim3(125, B), dim3(256), 0, stream, out);

    for (int s = 0; s <= T; ++s) {
        const float* hi = (s & 1) ? h1 : h0;
        const float* ci = (s & 1) ? c1 : c0;
        float* ho = (s & 1) ? h0 : h1;
        float* co = (s & 1) ? c0 : c1;
        hipLaunchKernelGGL(lstm_step, dim3(128, B / BPB), dim3(256), 0, stream,
                           features, captions, emb, W_ih, W_hh, b_ih, b_hh,
                           hi, ci, ho, co, hseq_bf, s);
    }

    hipLaunchKernelGGL(proj_gemm, dim3(V / 128, (T * B) / 128), dim3(256), 0, stream,
                       hseq_bf, wout_bf, b_out, out);
}